// Round 10
// baseline (138.117 us; speedup 1.0000x reference)
//
#include <hip/hip_runtime.h>
#include <hip/hip_bf16.h>
#include <stdint.h>
#include <stddef.h>

// ---------- types ----------
typedef __attribute__((ext_vector_type(8))) short bfrag8;   // 8 bf16 in 4 VGPRs
typedef __attribute__((ext_vector_type(4))) float facc4;    // MFMA accumulator

#define SCALING 0.17677669529663687f   // 32^-0.5

__device__ __forceinline__ unsigned short f2bf(float f) {
  union { float f; unsigned u; } v; v.f = f;
  unsigned r = v.u + 0x7fffu + ((v.u >> 16) & 1u);   // RNE
  return (unsigned short)(r >> 16);
}

// ---------------------------------------------------------------------------
// Kernel 1: fp32 -> bf16 convert for query, W_in, W_out
// ---------------------------------------------------------------------------
__global__ __launch_bounds__(256)
void convert_bf16(const float* __restrict__ q, const float* __restrict__ wi,
                  const float* __restrict__ wo,
                  unsigned short* __restrict__ qb, unsigned short* __restrict__ wib,
                  unsigned short* __restrict__ wob) {
  int t = blockIdx.x * 256 + threadIdx.x;
  const float4* src; unsigned short* dst; int idx;
  if (t < 524288)            { src = (const float4*)q;  dst = qb;  idx = t; }
  else if (t < 524288+196608){ src = (const float4*)wi; dst = wib; idx = t - 524288; }
  else                       { src = (const float4*)wo; dst = wob; idx = t - 720896; }
  float4 v = src[idx];
  ushort4 o;
  o.x = f2bf(v.x); o.y = f2bf(v.y); o.z = f2bf(v.z); o.w = f2bf(v.w);
  *(ushort4*)(dst + (size_t)idx * 4) = o;
}

// ---------------------------------------------------------------------------
// Kernel 2/5: GEMM  C[M x N] = A[M x 512] * B[N x 512]^T
// MODE 0: qkv epilogue; MODE 1: out epilogue
// ---------------------------------------------------------------------------
template<int MODE>
__global__ __launch_bounds__(256, 2)
void gemm_bt(const unsigned short* __restrict__ A, const unsigned short* __restrict__ Bw,
             const float* __restrict__ bias,
             unsigned short* __restrict__ oQ, unsigned short* __restrict__ oK,
             unsigned short* __restrict__ oV, float* __restrict__ oF) {
  constexpr int K = 512;
  __shared__ __align__(16) unsigned short lA[2][64 * 32];
  __shared__ __align__(16) unsigned short lB[2][128 * 32];
  const int t = threadIdx.x;
  const int w = t >> 6, l = t & 63;
  const int lr = l & 15, lg = l >> 4;
  const int mBase = blockIdx.x * 64;
  const int nBase = blockIdx.y * 128;
  const int wr = w >> 1, wc = w & 1;

  facc4 acc[2][4];
#pragma unroll
  for (int i = 0; i < 2; i++)
#pragma unroll
    for (int j = 0; j < 4; j++) acc[i][j] = (facc4){0.f, 0.f, 0.f, 0.f};

  const int arow = t & 63, aslot = t >> 6;
  const unsigned short* aSrc = A + (size_t)(mBase + arow) * K + aslot * 8;
  const int bcol0 = t & 127, bslot0 = t >> 7;
  const int bcol1 = (256 + t) & 127, bslot1 = (256 + t) >> 7;
  const unsigned short* bSrc0 = Bw + (size_t)(nBase + bcol0) * K + bslot0 * 8;
  const unsigned short* bSrc1 = Bw + (size_t)(nBase + bcol1) * K + bslot1 * 8;

  auto stage = [&](int ks, int buf) {
    const int kB = ks * 32;
    *(int4*)(&lA[buf][(size_t)t * 8])         = *(const int4*)(aSrc + kB);
    *(int4*)(&lB[buf][(size_t)t * 8])         = *(const int4*)(bSrc0 + kB);
    *(int4*)(&lB[buf][(size_t)(256 + t) * 8]) = *(const int4*)(bSrc1 + kB);
  };

  stage(0, 0);
  __syncthreads();
#pragma unroll 1
  for (int ks = 0; ks < 16; ks++) {
    const int buf = ks & 1;
    if (ks < 15) stage(ks + 1, buf ^ 1);
    bfrag8 af[2], bfr[4];
#pragma unroll
    for (int qi = 0; qi < 2; qi++)
      af[qi] = *(const bfrag8*)(&lA[buf][(lg * 64 + wr * 32 + qi * 16 + lr) * 8]);
#pragma unroll
    for (int nj = 0; nj < 4; nj++)
      bfr[nj] = *(const bfrag8*)(&lB[buf][(lg * 128 + wc * 64 + nj * 16 + lr) * 8]);
#pragma unroll
    for (int qi = 0; qi < 2; qi++)
#pragma unroll
      for (int nj = 0; nj < 4; nj++)
        acc[qi][nj] = __builtin_amdgcn_mfma_f32_16x16x32_bf16(af[qi], bfr[nj], acc[qi][nj], 0, 0, 0);
    __syncthreads();
  }

#pragma unroll
  for (int qi = 0; qi < 2; qi++)
#pragma unroll
    for (int nj = 0; nj < 4; nj++) {
      int m0 = mBase + wr * 32 + qi * 16 + lg * 4;
      int o = nBase + wc * 64 + nj * 16 + lr;
      float bv = bias[o];
#pragma unroll
      for (int r = 0; r < 4; r++) {
        float v = acc[qi][nj][r] + bv;
        int mm = m0 + r;
        if (MODE == 0) {
          int n = mm >> 2, g = mm & 3;
          int chunk = o >> 9, cc = o & 511, h = cc >> 5, d = cc & 31;
          size_t oidx = ((size_t)(g * 16 + h) * 1024 + n) * 32 + d;
          if (chunk == 0)      oQ[oidx] = f2bf(v * SCALING);
          else if (chunk == 1) oK[oidx] = f2bf(v);
          else                 oV[oidx] = f2bf(v);
        } else {
          oF[(size_t)mm * 512 + o] = v;
        }
      }
    }
}

// ---------------------------------------------------------------------------
// Kernel 3: V [gh][n][32] -> Vt [gh][32][n]   (grid 64 x 4, 256-row tiles)
// ---------------------------------------------------------------------------
__global__ __launch_bounds__(256)
void transpose_v(const unsigned short* __restrict__ V, unsigned short* __restrict__ Vt) {
  __shared__ unsigned short tile[32][264];
  const int gh = blockIdx.x, n0 = blockIdx.y * 256;
  const int t = threadIdx.x;
  const unsigned short* src = V + ((size_t)gh * 1024 + n0) * 32;
#pragma unroll
  for (int c = 0; c < 4; c++) {
    int j = c * 256 + t; int row = j >> 2, d0 = (j & 3) * 8;
    bfrag8 v = *(const bfrag8*)(src + (size_t)row * 32 + d0);
#pragma unroll
    for (int i = 0; i < 8; i++) tile[d0 + i][row] = (unsigned short)v[i];
  }
  __syncthreads();
  unsigned short* dst = Vt + (size_t)gh * 32 * 1024 + n0;
#pragma unroll
  for (int c = 0; c < 4; c++) {
    int j = c * 256 + t; int d = j >> 5, n8 = (j & 31) * 8;
    *(bfrag8*)(dst + (size_t)d * 1024 + n8) = *(const bfrag8*)(&tile[d][n8]);
  }
}

// ---------------------------------------------------------------------------
// Kernel 4: fused flash attention — round-10: FULL-STREAM CHUNKED STAGING.
// The decisive read-pattern experiment. r3 compute body verbatim; ONLY the
// bias delivery changes: per wave, per 256-col chunk, 16x global_load_lds
// where each instruction reads ONE FULL ROW's 1 KB CONTIGUOUSLY (64 lanes x
// 16 B) — identical footprint to the 6.3 TB/s copy ubench. Rows are the
// wave's OWN 16 q-rows -> zero barriers, waves free-run; 2 blocks/CU give
// cross-block stage/compute overlap (what r8's phase-drain lacked).
// LDS biasC[64][258] f32: pad = 2 dwords -> compute's (16-lane x 4-row)
// C-operand reads land 2 lanes/bank (free). 74 KB -> 2 blocks/CU.
// Evidence so far: bias at ~2.6 TB/s invariant under request size (r5),
// delivery path (r6), phase (r7), run length 512 B (r9). If this full-stream
// variant also lands ~2.6, the read ceiling is pattern-independent and r3
// is the roofline configuration.
// ---------------------------------------------------------------------------
__global__ __launch_bounds__(256)
void attn_kernel(const unsigned short* __restrict__ Qs, const unsigned short* __restrict__ Ks,
                 const unsigned short* __restrict__ Vt, const float* __restrict__ biasG,
                 unsigned short* __restrict__ Out) {
  __shared__ __align__(16) float biasC[64][258];            // 66 KB
  __shared__ __align__(16) unsigned short Pl[4][16 * 64];   // 8 KB per-wave P
  const int gh = blockIdx.x, q0 = blockIdx.y * 64;
  const int t = threadIdx.x, w = t >> 6, l = t & 63;
  const int lr = l & 15, lg = l >> 4;

  const unsigned short* Qg = Qs + (size_t)gh * 32768;
  const unsigned short* Kg = Ks + (size_t)gh * 32768;
  const unsigned short* Vg = Vt + (size_t)gh * 32768;
  // wave's 16 bias rows: q = q0 + w*16 + i
  const float* Bw = biasG + (size_t)gh * 1048576 + (size_t)(q0 + w * 16) * 1024;

  bfrag8 qf = *(const bfrag8*)(Qg + (size_t)(q0 + w * 16 + lr) * 32 + lg * 8);

  facc4 accO[2];
  accO[0] = (facc4){0.f, 0.f, 0.f, 0.f};
  accO[1] = (facc4){0.f, 0.f, 0.f, 0.f};
  float mrun[4], lrun[4];
#pragma unroll
  for (int r = 0; r < 4; r++) { mrun[r] = -3.0e38f; lrun[r] = 0.f; }

  unsigned short* Pw = Pl[w];

#pragma unroll 1
  for (int c = 0; c < 4; c++) {
    // stage chunk c: wave w stages its own rows w*16+i; one instruction =
    // one row's 1 KB contiguous (lane l -> bytes l*16..l*16+15)
#pragma unroll
    for (int i = 0; i < 16; i++) {
      __builtin_amdgcn_global_load_lds(
          (const __attribute__((address_space(1))) unsigned int*)(Bw + (size_t)i * 1024 + c * 256 + l * 4),
          (__attribute__((address_space(3))) unsigned int*)(&biasC[w * 16 + i][0]),
          16, 0, 0);
    }
    asm volatile("s_waitcnt vmcnt(0)" ::: "memory");

#pragma unroll 1
    for (int ktl = 0; ktl < 4; ktl++) {
      const int kb = c * 256 + ktl * 64;
      // bias from LDS -> MFMA C operand (2-way bank aliasing = free)
      facc4 sc[4];
#pragma unroll
      for (int j = 0; j < 4; j++)
#pragma unroll
        for (int r = 0; r < 4; r++)
          sc[j][r] = biasC[w * 16 + lg * 4 + r][ktl * 64 + j * 16 + lr];
      // QK^T accumulating onto the bias
#pragma unroll
      for (int j = 0; j < 4; j++) {
        bfrag8 kf = *(const bfrag8*)(Kg + (size_t)(kb + j * 16 + lr) * 32 + lg * 8);
        sc[j] = __builtin_amdgcn_mfma_f32_16x16x32_bf16(qf, kf, sc[j], 0, 0, 0);
      }
      // row max over this tile (16-lane column groups)
      float tm[4];
#pragma unroll
      for (int r = 0; r < 4; r++) tm[r] = -3.0e38f;
#pragma unroll
      for (int j = 0; j < 4; j++)
#pragma unroll
        for (int r = 0; r < 4; r++) tm[r] = fmaxf(tm[r], sc[j][r]);
#pragma unroll
      for (int mk = 1; mk < 16; mk <<= 1)
#pragma unroll
        for (int r = 0; r < 4; r++) tm[r] = fmaxf(tm[r], __shfl_xor(tm[r], mk, 64));
      // online softmax update
      float scale[4];
#pragma unroll
      for (int r = 0; r < 4; r++) {
        float mn = fmaxf(mrun[r], tm[r]);
        scale[r] = __expf(mrun[r] - mn);
        mrun[r] = mn;
      }
      float rs[4] = {0.f, 0.f, 0.f, 0.f};
#pragma unroll
      for (int j = 0; j < 4; j++)
#pragma unroll
        for (int r = 0; r < 4; r++) {
          float p = __expf(sc[j][r] - mrun[r]);
          rs[r] += p;
          int row = lg * 4 + r, col = j * 16 + lr;
          int byte = (row * 128 + col * 2) ^ ((row & 7) << 4);
          *(unsigned short*)((char*)Pw + byte) = f2bf(p);
        }
#pragma unroll
      for (int mk = 1; mk < 16; mk <<= 1)
#pragma unroll
        for (int r = 0; r < 4; r++) rs[r] += __shfl_xor(rs[r], mk, 64);
#pragma unroll
      for (int r = 0; r < 4; r++) lrun[r] = lrun[r] * scale[r] + rs[r];
#pragma unroll
      for (int h = 0; h < 2; h++)
#pragma unroll
        for (int r = 0; r < 4; r++) accO[h][r] *= scale[r];
      // PV (P A-frags from own-wave LDS; V B-frags 16B-contiguous from Vt)
#pragma unroll
      for (int ksb = 0; ksb < 2; ksb++) {
        int byte = (lr * 128 + (ksb * 32 + lg * 8) * 2) ^ ((lr & 7) << 4);
        bfrag8 pf = *(const bfrag8*)((char*)Pw + byte);
#pragma unroll
        for (int h = 0; h < 2; h++) {
          bfrag8 vf = *(const bfrag8*)(Vg + (size_t)(h * 16 + lr) * 1024 + kb + ksb * 32 + lg * 8);
          accO[h] = __builtin_amdgcn_mfma_f32_16x16x32_bf16(pf, vf, accO[h], 0, 0, 0);
        }
      }
    }
  }

  // epilogue: O / l  -> attn_out bf16 [4096, 512]
  const int g = gh >> 4, hh = gh & 15;
#pragma unroll
  for (int h = 0; h < 2; h++)
#pragma unroll
    for (int r = 0; r < 4; r++) {
      int q = q0 + w * 16 + lg * 4 + r;
      float v = accO[h][r] / lrun[r];
      int e = hh * 32 + h * 16 + lr;
      Out[(size_t)(q * 4 + g) * 512 + e] = f2bf(v);
    }
}

// ---------------------------------------------------------------------------
extern "C" void kernel_launch(void* const* d_in, const int* in_sizes, int n_in,
                              void* d_out, int out_size, void* d_ws, size_t ws_size,
                              hipStream_t stream) {
  (void)in_sizes; (void)n_in; (void)out_size; (void)ws_size;
  const float* query = (const float*)d_in[0];
  const float* abias = (const float*)d_in[1];
  const float* W_in  = (const float*)d_in[2];
  const float* b_in  = (const float*)d_in[3];
  const float* W_out = (const float*)d_in[4];
  const float* b_out = (const float*)d_in[5];
  float* out = (float*)d_out;
  char* ws = (char*)d_ws;
  unsigned short* qbf  = (unsigned short*)(ws);             // 4 MB
  unsigned short* wibf = (unsigned short*)(ws + 4194304);   // 1.5 MB
  unsigned short* wobf = (unsigned short*)(ws + 5767168);   // 0.5 MB
  unsigned short* Qs   = (unsigned short*)(ws + 6291456);   // 4 MB  [gh][n][d]
  unsigned short* Ks   = (unsigned short*)(ws + 10485760);  // 4 MB  [gh][n][d]
  unsigned short* Vv   = (unsigned short*)(ws + 14680064);  // 4 MB  [gh][n][d]
  unsigned short* Vt   = (unsigned short*)(ws + 18874368);  // 4 MB  [gh][d][n]
  unsigned short* attO = (unsigned short*)(ws + 23068672);  // 4 MB  [m][e]

  convert_bf16<<<3072, 256, 0, stream>>>(query, W_in, W_out, qbf, wibf, wobf);
  gemm_bt<0><<<dim3(64, 12), 256, 0, stream>>>(qbf, wibf, b_in, Qs, Ks, Vv, nullptr);
  transpose_v<<<dim3(64, 4), 256, 0, stream>>>(Vv, Vt);
  attn_kernel<<<dim3(64, 16), 256, 0, stream>>>(Qs, Ks, Vt, abias, attO);
  gemm_bt<1><<<dim3(64, 4), 256, 0, stream>>>(attO, wobf, b_out, nullptr, nullptr, nullptr, out);
}

// Round 11
// 124.885 us; speedup vs baseline: 1.1060x; 1.1060x over previous
//
#include <hip/hip_runtime.h>
#include <hip/hip_bf16.h>
#include <stdint.h>
#include <stddef.h>

// ---------- types ----------
typedef __attribute__((ext_vector_type(8))) short bfrag8;   // 8 bf16 in 4 VGPRs
typedef __attribute__((ext_vector_type(4))) float facc4;    // MFMA accumulator

#define SCALING 0.17677669529663687f   // 32^-0.5

__device__ __forceinline__ unsigned short f2bf(float f) {
  union { float f; unsigned u; } v; v.f = f;
  unsigned r = v.u + 0x7fffu + ((v.u >> 16) & 1u);   // RNE
  return (unsigned short)(r >> 16);
}

// ---------------------------------------------------------------------------
// Kernel 1: fp32 -> bf16 convert for query, W_in, W_out
// ---------------------------------------------------------------------------
__global__ __launch_bounds__(256)
void convert_bf16(const float* __restrict__ q, const float* __restrict__ wi,
                  const float* __restrict__ wo,
                  unsigned short* __restrict__ qb, unsigned short* __restrict__ wib,
                  unsigned short* __restrict__ wob) {
  int t = blockIdx.x * 256 + threadIdx.x;
  const float4* src; unsigned short* dst; int idx;
  if (t < 524288)            { src = (const float4*)q;  dst = qb;  idx = t; }
  else if (t < 524288+196608){ src = (const float4*)wi; dst = wib; idx = t - 524288; }
  else                       { src = (const float4*)wo; dst = wob; idx = t - 720896; }
  float4 v = src[idx];
  ushort4 o;
  o.x = f2bf(v.x); o.y = f2bf(v.y); o.z = f2bf(v.z); o.w = f2bf(v.w);
  *(ushort4*)(dst + (size_t)idx * 4) = o;
}

// ---------------------------------------------------------------------------
// Kernel 2/5: GEMM  C[M x N] = A[M x 512] * B[N x 512]^T
// MODE 0: qkv epilogue; MODE 1: out epilogue
// ---------------------------------------------------------------------------
template<int MODE>
__global__ __launch_bounds__(256, 2)
void gemm_bt(const unsigned short* __restrict__ A, const unsigned short* __restrict__ Bw,
             const float* __restrict__ bias,
             unsigned short* __restrict__ oQ, unsigned short* __restrict__ oK,
             unsigned short* __restrict__ oV, float* __restrict__ oF) {
  constexpr int K = 512;
  __shared__ __align__(16) unsigned short lA[2][64 * 32];
  __shared__ __align__(16) unsigned short lB[2][128 * 32];
  const int t = threadIdx.x;
  const int w = t >> 6, l = t & 63;
  const int lr = l & 15, lg = l >> 4;
  const int mBase = blockIdx.x * 64;
  const int nBase = blockIdx.y * 128;
  const int wr = w >> 1, wc = w & 1;

  facc4 acc[2][4];
#pragma unroll
  for (int i = 0; i < 2; i++)
#pragma unroll
    for (int j = 0; j < 4; j++) acc[i][j] = (facc4){0.f, 0.f, 0.f, 0.f};

  const int arow = t & 63, aslot = t >> 6;
  const unsigned short* aSrc = A + (size_t)(mBase + arow) * K + aslot * 8;
  const int bcol0 = t & 127, bslot0 = t >> 7;
  const int bcol1 = (256 + t) & 127, bslot1 = (256 + t) >> 7;
  const unsigned short* bSrc0 = Bw + (size_t)(nBase + bcol0) * K + bslot0 * 8;
  const unsigned short* bSrc1 = Bw + (size_t)(nBase + bcol1) * K + bslot1 * 8;

  auto stage = [&](int ks, int buf) {
    const int kB = ks * 32;
    *(int4*)(&lA[buf][(size_t)t * 8])         = *(const int4*)(aSrc + kB);
    *(int4*)(&lB[buf][(size_t)t * 8])         = *(const int4*)(bSrc0 + kB);
    *(int4*)(&lB[buf][(size_t)(256 + t) * 8]) = *(const int4*)(bSrc1 + kB);
  };

  stage(0, 0);
  __syncthreads();
#pragma unroll 1
  for (int ks = 0; ks < 16; ks++) {
    const int buf = ks & 1;
    if (ks < 15) stage(ks + 1, buf ^ 1);
    bfrag8 af[2], bfr[4];
#pragma unroll
    for (int qi = 0; qi < 2; qi++)
      af[qi] = *(const bfrag8*)(&lA[buf][(lg * 64 + wr * 32 + qi * 16 + lr) * 8]);
#pragma unroll
    for (int nj = 0; nj < 4; nj++)
      bfr[nj] = *(const bfrag8*)(&lB[buf][(lg * 128 + wc * 64 + nj * 16 + lr) * 8]);
#pragma unroll
    for (int qi = 0; qi < 2; qi++)
#pragma unroll
      for (int nj = 0; nj < 4; nj++)
        acc[qi][nj] = __builtin_amdgcn_mfma_f32_16x16x32_bf16(af[qi], bfr[nj], acc[qi][nj], 0, 0, 0);
    __syncthreads();
  }

#pragma unroll
  for (int qi = 0; qi < 2; qi++)
#pragma unroll
    for (int nj = 0; nj < 4; nj++) {
      int m0 = mBase + wr * 32 + qi * 16 + lg * 4;
      int o = nBase + wc * 64 + nj * 16 + lr;
      float bv = bias[o];
#pragma unroll
      for (int r = 0; r < 4; r++) {
        float v = acc[qi][nj][r] + bv;
        int mm = m0 + r;
        if (MODE == 0) {
          int n = mm >> 2, g = mm & 3;
          int chunk = o >> 9, cc = o & 511, h = cc >> 5, d = cc & 31;
          size_t oidx = ((size_t)(g * 16 + h) * 1024 + n) * 32 + d;
          if (chunk == 0)      oQ[oidx] = f2bf(v * SCALING);
          else if (chunk == 1) oK[oidx] = f2bf(v);
          else                 oV[oidx] = f2bf(v);
        } else {
          oF[(size_t)mm * 512 + o] = v;
        }
      }
    }
}

// ---------------------------------------------------------------------------
// Kernel 3: V [gh][n][32] -> Vt [gh][32][n]   (grid 64 x 4, 256-row tiles)
// ---------------------------------------------------------------------------
__global__ __launch_bounds__(256)
void transpose_v(const unsigned short* __restrict__ V, unsigned short* __restrict__ Vt) {
  __shared__ unsigned short tile[32][264];
  const int gh = blockIdx.x, n0 = blockIdx.y * 256;
  const int t = threadIdx.x;
  const unsigned short* src = V + ((size_t)gh * 1024 + n0) * 32;
#pragma unroll
  for (int c = 0; c < 4; c++) {
    int j = c * 256 + t; int row = j >> 2, d0 = (j & 3) * 8;
    bfrag8 v = *(const bfrag8*)(src + (size_t)row * 32 + d0);
#pragma unroll
    for (int i = 0; i < 8; i++) tile[d0 + i][row] = (unsigned short)v[i];
  }
  __syncthreads();
  unsigned short* dst = Vt + (size_t)gh * 32 * 1024 + n0;
#pragma unroll
  for (int c = 0; c < 4; c++) {
    int j = c * 256 + t; int d = j >> 5, n8 = (j & 31) * 8;
    *(bfrag8*)(dst + (size_t)d * 1024 + n8) = *(const bfrag8*)(&tile[d][n8]);
  }
}

// ---------------------------------------------------------------------------
// Kernel 4: fused flash attention — round-11: Q-SPLIT OCCUPANCY DOUBLE.
// r3's kernel body VERBATIM; the ONLY change is the work decomposition:
// q-tile 64 -> 32, block = 2 waves (128 thr), grid (64 gh, 32 q-tiles) =
// 2048 blocks = 16 blocks/CU = 32 waves/CU = 8 waves/SIMD (VGPR=60 allows
// it; LDS 4 KB/block is nowhere near limiting).
// WHY: r3's 1024-block grid capped the machine at 4 waves/SIMD. All bias-
// delivery-pattern experiments (r5-r10) were null at ~2.6 TB/s delivered;
// the one untested lever is total wave concurrency (r4's split-K doubled it
// but bundled 33 MB of partial traffic + a combine kernel — dirty test).
// Q-split has ZERO overhead: no extra traffic, no extra kernels, waves were
// already independent (no barriers). Pure concurrency experiment.
// ---------------------------------------------------------------------------
__global__ __launch_bounds__(128)
void attn_kernel(const unsigned short* __restrict__ Qs, const unsigned short* __restrict__ Ks,
                 const unsigned short* __restrict__ Vt, const float* __restrict__ biasG,
                 unsigned short* __restrict__ Out) {
  __shared__ __align__(16) unsigned short Pl[2][16 * 64];   // 4 KB, per-wave P tile
  const int gh = blockIdx.x, q0 = blockIdx.y * 32;
  const int t = threadIdx.x, w = t >> 6, l = t & 63;
  const int lr = l & 15, lg = l >> 4;

  const unsigned short* Qg = Qs + (size_t)gh * 32768;
  const unsigned short* Kg = Ks + (size_t)gh * 32768;
  const unsigned short* Vg = Vt + (size_t)gh * 32768;
  // per-thread bias base: row = q0 + w*16 + lg*4 (+r), col = lr (+j*16 + kb)
  const float* Bt = biasG + (size_t)gh * 1048576 + (size_t)(q0 + w * 16 + lg * 4) * 1024 + lr;

  bfrag8 qf = *(const bfrag8*)(Qg + (size_t)(q0 + w * 16 + lr) * 32 + lg * 8);

  facc4 accO[2];
  accO[0] = (facc4){0.f, 0.f, 0.f, 0.f};
  accO[1] = (facc4){0.f, 0.f, 0.f, 0.f};
  float mrun[4], lrun[4];
#pragma unroll
  for (int r = 0; r < 4; r++) { mrun[r] = -3.0e38f; lrun[r] = 0.f; }

  unsigned short* Pw = Pl[w];

#pragma unroll 1
  for (int kt = 0; kt < 16; kt++) {
    const int kb = kt * 64;
    // bias -> MFMA C operand (16 scalar dword loads, exact C/D lane layout)
    facc4 sc[4];
#pragma unroll
    for (int j = 0; j < 4; j++)
#pragma unroll
      for (int r = 0; r < 4; r++)
        sc[j][r] = Bt[(size_t)r * 1024 + kb + j * 16];
    // QK^T accumulating onto the bias
#pragma unroll
    for (int j = 0; j < 4; j++) {
      bfrag8 kf = *(const bfrag8*)(Kg + (size_t)(kb + j * 16 + lr) * 32 + lg * 8);
      sc[j] = __builtin_amdgcn_mfma_f32_16x16x32_bf16(qf, kf, sc[j], 0, 0, 0);
    }
    // row max over this tile (16-lane column groups)
    float tm[4];
#pragma unroll
    for (int r = 0; r < 4; r++) tm[r] = -3.0e38f;
#pragma unroll
    for (int j = 0; j < 4; j++)
#pragma unroll
      for (int r = 0; r < 4; r++) tm[r] = fmaxf(tm[r], sc[j][r]);
#pragma unroll
    for (int mk = 1; mk < 16; mk <<= 1)
#pragma unroll
      for (int r = 0; r < 4; r++) tm[r] = fmaxf(tm[r], __shfl_xor(tm[r], mk, 64));
    // online softmax update
    float scale[4];
#pragma unroll
    for (int r = 0; r < 4; r++) {
      float mn = fmaxf(mrun[r], tm[r]);
      scale[r] = __expf(mrun[r] - mn);
      mrun[r] = mn;
    }
    float rs[4] = {0.f, 0.f, 0.f, 0.f};
#pragma unroll
    for (int j = 0; j < 4; j++)
#pragma unroll
      for (int r = 0; r < 4; r++) {
        float p = __expf(sc[j][r] - mrun[r]);
        rs[r] += p;
        int row = lg * 4 + r, col = j * 16 + lr;
        int byte = (row * 128 + col * 2) ^ ((row & 7) << 4);
        *(unsigned short*)((char*)Pw + byte) = f2bf(p);
      }
#pragma unroll
    for (int mk = 1; mk < 16; mk <<= 1)
#pragma unroll
      for (int r = 0; r < 4; r++) rs[r] += __shfl_xor(rs[r], mk, 64);
#pragma unroll
    for (int r = 0; r < 4; r++) lrun[r] = lrun[r] * scale[r] + rs[r];
#pragma unroll
    for (int h = 0; h < 2; h++)
#pragma unroll
      for (int r = 0; r < 4; r++) accO[h][r] *= scale[r];
    // PV (P A-frags from own-wave LDS; V B-frags 16B-contiguous from Vt)
#pragma unroll
    for (int ksb = 0; ksb < 2; ksb++) {
      int byte = (lr * 128 + (ksb * 32 + lg * 8) * 2) ^ ((lr & 7) << 4);
      bfrag8 pf = *(const bfrag8*)((char*)Pw + byte);
#pragma unroll
      for (int h = 0; h < 2; h++) {
        bfrag8 vf = *(const bfrag8*)(Vg + (size_t)(h * 16 + lr) * 1024 + kb + ksb * 32 + lg * 8);
        accO[h] = __builtin_amdgcn_mfma_f32_16x16x32_bf16(pf, vf, accO[h], 0, 0, 0);
      }
    }
  }

  // epilogue: O / l  -> attn_out bf16 [4096, 512]
  const int g = gh >> 4, hh = gh & 15;
#pragma unroll
  for (int h = 0; h < 2; h++)
#pragma unroll
    for (int r = 0; r < 4; r++) {
      int q = q0 + w * 16 + lg * 4 + r;
      float v = accO[h][r] / lrun[r];
      int e = hh * 32 + h * 16 + lr;
      Out[(size_t)(q * 4 + g) * 512 + e] = f2bf(v);
    }
}

// ---------------------------------------------------------------------------
extern "C" void kernel_launch(void* const* d_in, const int* in_sizes, int n_in,
                              void* d_out, int out_size, void* d_ws, size_t ws_size,
                              hipStream_t stream) {
  (void)in_sizes; (void)n_in; (void)out_size; (void)ws_size;
  const float* query = (const float*)d_in[0];
  const float* abias = (const float*)d_in[1];
  const float* W_in  = (const float*)d_in[2];
  const float* b_in  = (const float*)d_in[3];
  const float* W_out = (const float*)d_in[4];
  const float* b_out = (const float*)d_in[5];
  float* out = (float*)d_out;
  char* ws = (char*)d_ws;
  unsigned short* qbf  = (unsigned short*)(ws);             // 4 MB
  unsigned short* wibf = (unsigned short*)(ws + 4194304);   // 1.5 MB
  unsigned short* wobf = (unsigned short*)(ws + 5767168);   // 0.5 MB
  unsigned short* Qs   = (unsigned short*)(ws + 6291456);   // 4 MB  [gh][n][d]
  unsigned short* Ks   = (unsigned short*)(ws + 10485760);  // 4 MB  [gh][n][d]
  unsigned short* Vv   = (unsigned short*)(ws + 14680064);  // 4 MB  [gh][n][d]
  unsigned short* Vt   = (unsigned short*)(ws + 18874368);  // 4 MB  [gh][d][n]
  unsigned short* attO = (unsigned short*)(ws + 23068672);  // 4 MB  [m][e]

  convert_bf16<<<3072, 256, 0, stream>>>(query, W_in, W_out, qbf, wibf, wobf);
  gemm_bt<0><<<dim3(64, 12), 256, 0, stream>>>(qbf, wibf, b_in, Qs, Ks, Vv, nullptr);
  transpose_v<<<dim3(64, 4), 256, 0, stream>>>(Vv, Vt);
  attn_kernel<<<dim3(64, 32), 128, 0, stream>>>(Qs, Ks, Vt, abias, attO);
  gemm_bt<1><<<dim3(64, 4), 256, 0, stream>>>(attO, wobf, b_out, nullptr, nullptr, nullptr, out);
}